// Round 11
// baseline (204.542 us; speedup 1.0000x reference)
//
#include <hip/hip_runtime.h>
#include <math.h>

#define B_  2
#define T_  2048
#define D_  1024
#define H_  16
#define HS_ 64
#define M_  (B_*T_)   // 4096

typedef __bf16 bf16x8 __attribute__((ext_vector_type(8)));
typedef float  f32x4  __attribute__((ext_vector_type(4)));
typedef unsigned short u16;

// native HW cvt (v_cvt_pk_bf16_f32 when paired) — RNE, 1 inst vs 3-4 manual
static __device__ __forceinline__ u16 f2bf(float f) {
    __bf16 h = (__bf16)f;
    return *reinterpret_cast<u16*>(&h);
}

// async global->LDS, 16B/lane; LDS dest is lane-linear (base + lane*16).
static __device__ __forceinline__ void glds16(const u16* g, u16* l) {
    __builtin_amdgcn_global_load_lds(
        (const __attribute__((address_space(1))) void*)g,
        (__attribute__((address_space(3))) void*)l, 16, 0, 0);
}

// ---------------- fused prep: cast x, transpose+cast both weights ----------
__global__ __launch_bounds__(256) void prep_kernel(
    const float* __restrict__ x, const float* __restrict__ w_qkv,
    const float* __restrict__ w_out,
    u16* __restrict__ Xb, u16* __restrict__ WqkvT, u16* __restrict__ WoutT)
{
    int bid = blockIdx.x;
    if (bid < 4096) {                       // cast x
        int i = (bid * 256 + threadIdx.x) * 4;
        float4 v = *reinterpret_cast<const float4*>(x + i);
        ushort4 o;
        o.x = f2bf(v.x); o.y = f2bf(v.y); o.z = f2bf(v.z); o.w = f2bf(v.w);
        *reinterpret_cast<ushort4*>(Xb + i) = o;
        return;
    }
    const float* in; u16* out; int C; int c0, r0;
    if (bid < 4096 + 3072) {                // w_qkv (D x 3D) -> (3D x D)
        int t = bid - 4096;
        in = w_qkv; out = WqkvT; C = 3 * D_;
        c0 = (t % 96) * 32; r0 = (t / 96) * 32;
    } else {                                // w_out (D x D) -> (D x D)
        int t = bid - 7168;
        in = w_out; out = WoutT; C = D_;
        c0 = (t & 31) * 32; r0 = (t >> 5) * 32;
    }
    __shared__ float tile[32][33];
    int tr = threadIdx.x >> 3, tc4 = (threadIdx.x & 7) * 4;
    float4 v = *reinterpret_cast<const float4*>(in + (size_t)(r0 + tr) * C + c0 + tc4);
    tile[tr][tc4+0] = v.x; tile[tr][tc4+1] = v.y;
    tile[tr][tc4+2] = v.z; tile[tr][tc4+3] = v.w;
    __syncthreads();
    ushort4 o;
    o.x = f2bf(tile[tc4+0][tr]); o.y = f2bf(tile[tc4+1][tr]);
    o.z = f2bf(tile[tc4+2][tr]); o.w = f2bf(tile[tc4+3][tr]);
    *reinterpret_cast<ushort4*>(out + (size_t)(c0 + tr) * D_ + r0 + tc4) = o;
}

// ---------------- QKV GEMM: 4-phase-per-K-tile pipeline (R2) + XCD swizzle -
__global__ __launch_bounds__(512, 2) void gemm_qkv(
    const u16* __restrict__ A, const u16* __restrict__ Bt,
    const float* __restrict__ bias,
    u16* __restrict__ Qb, u16* __restrict__ Kb, u16* __restrict__ Vt)
{
    constexpr int K  = D_;        // 1024
    constexpr int NT = K / 64;    // 16

    __shared__ u16 LDS[2][2][2][8192];  // [buf][A|B][khalf][256r x 32k swz] = 128 KiB

    const int tid  = threadIdx.x;
    const int lane = tid & 63, wave = tid >> 6;
    const int wm = wave >> 2, wn = wave & 3;       // 2 x 4
    const int quad = lane >> 4, lr = lane & 15;

    const int lin = blockIdx.x + 16 * blockIdx.y;  // x-major dispatch order
    const int xcd = lin & 7, rr = lin >> 3;        // rr 0..23
    const int bm = (xcd & 3) * 4 + (rr & 3);
    const int bn = (xcd >> 2) * 6 + (rr >> 2);

    const u16* Ab = A  + (size_t)(bm * 256) * K;
    const u16* Bb = Bt + (size_t)(bn * 256) * K;

    const int r0 = tid >> 2;
    const int c0 = (tid & 3) ^ ((tid >> 3) & 3);
    const u16* sA0 = Ab + (size_t)r0 * K + c0 * 8;
    const u16* sA1 = sA0 + (size_t)128 * K;
    const u16* sB0 = Bb + (size_t)r0 * K + c0 * 8;
    const u16* sB1 = sB0 + (size_t)128 * K;
    const int d0 = tid * 8, d1 = (tid + 512) * 8;

    const int swz = (lr >> 1) & 3;
    const int eA = ((wm*128 + lr) * 4 + (quad ^ swz)) * 8;
    const int eB = ((wn*64  + lr) * 4 + (quad ^ swz)) * 8;

    f32x4 acc[8][4] = {};

#define STG(mat, kh, tt) do { \
        u16* _d = &LDS[(tt) & 1][mat][kh][0]; \
        const int _ko = (tt) * 64 + (kh) * 32; \
        glds16(((mat) ? sB0 : sA0) + _ko, _d + d0); \
        glds16(((mat) ? sB1 : sA1) + _ko, _d + d1); \
    } while (0)

#define MFMA_QUAD(mh) do { \
        __builtin_amdgcn_s_setprio(1); \
        _Pragma("unroll") \
        for (int i_ = 0; i_ < 4; ++i_) \
            _Pragma("unroll") \
            for (int j_ = 0; j_ < 4; ++j_) \
                acc[(mh)*4 + i_][j_] = __builtin_amdgcn_mfma_f32_16x16x32_bf16( \
                    a[i_], b[j_], acc[(mh)*4 + i_][j_], 0, 0, 0); \
        __builtin_amdgcn_s_setprio(0); \
    } while (0)

    STG(0,0,0); STG(1,0,0); STG(0,1,0); STG(1,1,0);
    asm volatile("s_waitcnt vmcnt(4)" ::: "memory");
    __builtin_amdgcn_s_barrier();

    for (int t = 0; t < NT; ++t) {
        const int cb = t & 1;
        const bool last = (t == NT - 1);
        const u16* Ar0 = &LDS[cb][0][0][0];
        const u16* Ar1 = &LDS[cb][0][1][0];
        const u16* Br0 = &LDS[cb][1][0][0];
        const u16* Br1 = &LDS[cb][1][1][0];
        bf16x8 a[4], b[4];

        // ---- phase A: k0, m-frags 0-3 (+ b k0) ----
        #pragma unroll
        for (int i = 0; i < 4; ++i) a[i] = *reinterpret_cast<const bf16x8*>(Ar0 + eA + i*512);
        #pragma unroll
        for (int j = 0; j < 4; ++j) b[j] = *reinterpret_cast<const bf16x8*>(Br0 + eB + j*512);
        if (!last) STG(0,0,t+1);
        __builtin_amdgcn_s_barrier();
        asm volatile("s_waitcnt lgkmcnt(0)" ::: "memory");
        MFMA_QUAD(0);
        __builtin_amdgcn_s_barrier();

        // ---- phase B: k0, m-frags 4-7 (b reused) ----
        #pragma unroll
        for (int i = 0; i < 4; ++i) a[i] = *reinterpret_cast<const bf16x8*>(Ar0 + eA + (i+4)*512);
        if (!last) STG(1,0,t+1);
        __builtin_amdgcn_s_barrier();
        asm volatile("s_waitcnt lgkmcnt(0)" ::: "memory");
        MFMA_QUAD(1);
        if (!last) { asm volatile("s_waitcnt vmcnt(4)" ::: "memory"); }
        else       { asm volatile("s_waitcnt vmcnt(0)" ::: "memory"); }
        __builtin_amdgcn_s_barrier();

        // ---- phase C: k1, m-frags 0-3 (+ b k1) ----
        #pragma unroll
        for (int i = 0; i < 4; ++i) a[i] = *reinterpret_cast<const bf16x8*>(Ar1 + eA + i*512);
        #pragma unroll
        for (int j = 0; j < 4; ++j) b[j] = *reinterpret_cast<const bf16x8*>(Br1 + eB + j*512);
        if (!last) STG(0,1,t+1);
        __builtin_amdgcn_s_barrier();
        asm volatile("s_waitcnt lgkmcnt(0)" ::: "memory");
        MFMA_QUAD(0);
        __builtin_amdgcn_s_barrier();

        // ---- phase D: k1, m-frags 4-7 ----
        #pragma unroll
        for (int i = 0; i < 4; ++i) a[i] = *reinterpret_cast<const bf16x8*>(Ar1 + eA + (i+4)*512);
        if (!last) STG(1,1,t+1);
        __builtin_amdgcn_s_barrier();
        asm volatile("s_waitcnt lgkmcnt(0)" ::: "memory");
        MFMA_QUAD(1);
        asm volatile("s_waitcnt vmcnt(4)" ::: "memory");
        __builtin_amdgcn_s_barrier();
    }
#undef STG
#undef MFMA_QUAD

    // -------- epilogue: scatter to Q (scale folded) / K / V^T --------
    #pragma unroll
    for (int i = 0; i < 8; ++i) {
        int m0 = bm*256 + wm*128 + i*16 + quad*4;   // 4-aligned
        #pragma unroll
        for (int j = 0; j < 4; ++j) {
            int ncol = bn*256 + wn*64 + j*16 + lr;
            float bv = bias[ncol];
            float v4[4];
            #pragma unroll
            for (int r = 0; r < 4; ++r) v4[r] = acc[i][j][r] + bv;
            int bb = m0 >> 11, t0 = m0 & (T_ - 1);
            int s = ncol >> 10, rem = ncol & 1023;
            int h = rem >> 6, d = rem & 63;
            int bh = bb * H_ + h;
            if (s == 0) {
                // fold softmax scale AND log2(e) (attn uses exp2): 0.125*log2e
                #pragma unroll
                for (int r = 0; r < 4; ++r)
                    Qb[((size_t)bh*T_ + t0 + r)*HS_ + d] = f2bf(v4[r] * 0.1803368801111244f);
            } else if (s == 1) {
                #pragma unroll
                for (int r = 0; r < 4; ++r)
                    Kb[((size_t)bh*T_ + t0 + r)*HS_ + d] = f2bf(v4[r]);
            } else {
                ushort4 o;   // consecutive t -> one 8B store
                o.x = f2bf(v4[0]); o.y = f2bf(v4[1]);
                o.z = f2bf(v4[2]); o.w = f2bf(v4[3]);
                *reinterpret_cast<ushort4*>(&Vt[((size_t)bh*HS_ + d)*T_ + t0]) = o;
            }
        }
    }
}

// ---------------- out-proj GEMM: 2-phase-per-K-tile pipeline (R3) ----------
__global__ __launch_bounds__(256, 2) void gemm_out(
    const u16* __restrict__ A, const u16* __restrict__ Bt,
    const float* __restrict__ bias, float* __restrict__ Cf)
{
    constexpr int K  = D_;        // 1024
    constexpr int N  = D_;
    constexpr int NT = K / 64;    // 16

    __shared__ u16 LDS[2][2][2][4096];  // [buf][A|B][khalf][128r x 32k swz] = 64 KiB

    const int tid  = threadIdx.x;
    const int lane = tid & 63, wave = tid >> 6;
    const int wm = wave >> 1, wn = wave & 1;       // 2 x 2
    const int quad = lane >> 4, lr = lane & 15;
    const int bm = blockIdx.x, bn = blockIdx.y;

    const u16* Ab = A  + (size_t)(bm * 128) * K;
    const u16* Bb = Bt + (size_t)(bn * 128) * K;

    const int r0 = tid >> 2;
    const int c0 = (tid & 3) ^ ((tid >> 3) & 3);
    const u16* sA0 = Ab + (size_t)r0 * K + c0 * 8;
    const u16* sA1 = sA0 + (size_t)64 * K;
    const u16* sB0 = Bb + (size_t)r0 * K + c0 * 8;
    const u16* sB1 = sB0 + (size_t)64 * K;
    const int d0 = tid * 8, d1 = (tid + 256) * 8;

    const int swz = (lr >> 1) & 3;
    const int eA = ((wm*64 + lr) * 4 + (quad ^ swz)) * 8;
    const int eB = ((wn*64 + lr) * 4 + (quad ^ swz)) * 8;

    f32x4 acc[4][4] = {};

#define STGO(kh, tt) do { \
        const int _ko = (tt) * 64 + (kh) * 32; \
        glds16(sA0 + _ko, &LDS[(tt) & 1][0][kh][0] + d0); \
        glds16(sA1 + _ko, &LDS[(tt) & 1][0][kh][0] + d1); \
        glds16(sB0 + _ko, &LDS[(tt) & 1][1][kh][0] + d0); \
        glds16(sB1 + _ko, &LDS[(tt) & 1][1][kh][0] + d1); \
    } while (0)

    STGO(0, 0); STGO(1, 0);
    asm volatile("s_waitcnt vmcnt(4)" ::: "memory");
    __builtin_amdgcn_s_barrier();

    for (int t = 0; t < NT; ++t) {
        const int cb = t & 1;
        const bool last = (t == NT - 1);
        bf16x8 a[4], b[4];

        // ---- phase 0: k-half 0 ----
        {
            const u16* Ar = &LDS[cb][0][0][0];
            const u16* Br = &LDS[cb][1][0][0];
            #pragma unroll
            for (int i = 0; i < 4; ++i) a[i] = *reinterpret_cast<const bf16x8*>(Ar + eA + i*512);
            #pragma unroll
            for (int j = 0; j < 4; ++j) b[j] = *reinterpret_cast<const bf16x8*>(Br + eB + j*512);
            if (!last) STGO(0, t+1);
            __builtin_amdgcn_s_barrier();
            asm volatile("s_waitcnt lgkmcnt(0)" ::: "memory");
            __builtin_amdgcn_s_setprio(1);
            #pragma unroll
            for (int i = 0; i < 4; ++i)
                #pragma unroll
                for (int j = 0; j < 4; ++j)
                    acc[i][j] = __builtin_amdgcn_mfma_f32_16x16x32_bf16(a[i], b[j], acc[i][j], 0, 0, 0);
            __builtin_amdgcn_s_setprio(0);
            if (!last) { asm volatile("s_waitcnt vmcnt(4)" ::: "memory"); }
            else       { asm volatile("s_waitcnt vmcnt(0)" ::: "memory"); }
            __builtin_amdgcn_s_barrier();
        }

        // ---- phase 1: k-half 1 ----
        {
            const u16* Ar = &LDS[cb][0][1][0];
            const u16* Br = &LDS[cb][1][1][0];
            #pragma unroll
            for (int i = 0; i < 4; ++i) a[i] = *reinterpret_cast<const bf16x8*>(Ar + eA + i*512);
            #pragma unroll
            for (int j = 0; j < 4; ++j) b[j] = *reinterpret_cast<const bf16x8*>(Br + eB + j*512);
            if (!last) STGO(1, t+1);
            __builtin_amdgcn_s_barrier();
            asm volatile("s_waitcnt lgkmcnt(0)" ::: "memory");
            __builtin_amdgcn_s_setprio(1);
            #pragma unroll
            for (int i = 0; i < 4; ++i)
                #pragma unroll
                for (int j = 0; j < 4; ++j)
                    acc[i][j] = __builtin_amdgcn_mfma_f32_16x16x32_bf16(a[i], b[j], acc[i][j], 0, 0, 0);
            __builtin_amdgcn_s_setprio(0);
            if (!last) { asm volatile("s_waitcnt vmcnt(4)" ::: "memory"); }
            __builtin_amdgcn_s_barrier();
        }
    }
#undef STGO

    #pragma unroll
    for (int i = 0; i < 4; ++i) {
        int m0 = bm*128 + wm*64 + i*16 + quad*4;
        #pragma unroll
        for (int j = 0; j < 4; ++j) {
            int ncol = bn*128 + wn*64 + j*16 + lr;
            float bv = bias[ncol];
            #pragma unroll
            for (int r = 0; r < 4; ++r)
                Cf[(size_t)(m0 + r) * N + ncol] = acc[i][j][r] + bv;
        }
    }
}

// ---------------- Flash attention: PAIRED q-tiles, swapped QK^T, PIPELINED -
// R10 math kept byte-identical. New schedule: cross-iteration pipeline —
// QK(j+1) MFMAs issue alongside softmax(j)+PV(j) (softmax consumes Sa from
// the PREVIOUS iteration's QK => exp2 stream hides under MFMA; Sa(j+1) not
// consumed until next iter => no MFMA-latency stall before softmax).
// Triple-buffered K/V (iter j: read V from buf[j%3], K from buf[(j+1)%3],
// write tile j+2 into buf[(j+2)%3]) => ONE raw barrier/iter, lgkmcnt-only
// (global prefetch loads stay in flight across it — no vmcnt drain).
__global__ __launch_bounds__(256) void attn_kernel(
    const u16* __restrict__ Qb, const u16* __restrict__ Kb,
    const u16* __restrict__ Vt, u16* __restrict__ Ob)
{
    __shared__ u16 Ks[3][64 * 64];     // 24 KB
    __shared__ u16 Vs[3][64 * 64];     // 24 KB
    __shared__ u16 Ps[4][2][16 * 64];  // 16 KB

    int tid  = threadIdx.x;
    int lane = tid & 63, wave = tid >> 6;          // wave 0..3
    int quad = lane >> 4, lr = lane & 15;

    int lin = blockIdx.x;                          // 512 blocks
    int bh  = (lin & 7) + 8 * ((lin >> 3) & 3);    // XCD-local bh (4 bh/XCD)
    int p   = lin >> 5;                            // 0..15
    int qlo = p, qhi = 31 - p;                     // qhi in [16,31]
    int rlo = qlo * 64 + wave * 16;
    int rhi = qhi * 64 + wave * 16;

    const u16* QpL = Qb + ((size_t)bh * T_ + rlo) * HS_;
    const u16* QpH = Qb + ((size_t)bh * T_ + rhi) * HS_;
    bf16x8 qfL[2], qfH[2];
    #pragma unroll
    for (int h2 = 0; h2 < 2; ++h2) {
        qfL[h2] = *reinterpret_cast<const bf16x8*>(QpL + lr*HS_ + h2*32 + quad*8);
        qfH[h2] = *reinterpret_cast<const bf16x8*>(QpH + lr*HS_ + h2*32 + quad*8);
    }

    f32x4 OaL[4] = {}, OaH[4] = {};
    float lsumL = 0.f, lsumH = 0.f;

    int e   = quad ^ (lr & 7);
    int rb0 = (lr * 8 + e) * 8;
    int rb1 = (lr * 8 + (e ^ 4)) * 8;
    int off64[4];
    #pragma unroll
    for (int nt = 0; nt < 4; ++nt)
        off64[nt] = (lr*8 + ((2*nt + (quad >> 1)) ^ (lr & 7)))*8 + (quad & 1)*4;
    u16* PsL = Ps[wave][0];
    u16* PsH = Ps[wave][1];

    int srow = tid >> 3;
    int scol = ((tid & 7) ^ (srow & 7)) * 8;
    const u16* kp0 = Kb + ((size_t)bh*T_ + srow     )*HS_ + scol;
    const u16* kp1 = Kb + ((size_t)bh*T_ + srow + 32)*HS_ + scol;
    const u16* vp0 = Vt + ((size_t)bh*HS_ + srow     )*T_ + scol;
    const u16* vp1 = Vt + ((size_t)bh*HS_ + srow + 32)*T_ + scol;

    bf16x8 kpre0, kpre1, vpre0, vpre1;

    u16 *KsV = Ks[0], *KsK = Ks[1], *KsW = Ks[2];
    u16 *VsV = Vs[0], *VsK = Vs[1], *VsW = Vs[2];

#define LOADREGS() do { \
    kpre0 = *reinterpret_cast<const bf16x8*>(kp0); \
    kpre1 = *reinterpret_cast<const bf16x8*>(kp1); \
    vpre0 = *reinterpret_cast<const bf16x8*>(vp0); \
    vpre1 = *reinterpret_cast<const bf16x8*>(vp1); \
    kp0 += 64*HS_; kp1 += 64*HS_; vp0 += 64; vp1 += 64; } while (0)

#define WRITEBUF(KD, VD) do { \
    reinterpret_cast<bf16x8*>(KD)[tid]       = kpre0; \
    reinterpret_cast<bf16x8*>(KD)[tid + 256] = kpre1; \
    reinterpret_cast<bf16x8*>(VD)[tid]       = vpre0; \
    reinterpret_cast<bf16x8*>(VD)[tid + 256] = vpre1; } while (0)

#define QKC(SH, SL, KB, LOC) do { \
    __builtin_amdgcn_s_setprio(1); \
    _Pragma("unroll") \
    for (int nt = 0; nt < 4; ++nt) { \
        bf16x8 bk0 = *reinterpret_cast<const bf16x8*>((KB) + rb0 + nt*1024); \
        bf16x8 bk1 = *reinterpret_cast<const bf16x8*>((KB) + rb1 + nt*1024); \
        f32x4 z = {}; \
        (SH)[nt] = __builtin_amdgcn_mfma_f32_16x16x32_bf16(bk0, qfH[0], z, 0, 0, 0); \
        (SH)[nt] = __builtin_amdgcn_mfma_f32_16x16x32_bf16(bk1, qfH[1], (SH)[nt], 0, 0, 0); \
        if (LOC) { \
            (SL)[nt] = __builtin_amdgcn_mfma_f32_16x16x32_bf16(bk0, qfL[0], z, 0, 0, 0); \
            (SL)[nt] = __builtin_amdgcn_mfma_f32_16x16x32_bf16(bk1, qfL[1], (SL)[nt], 0, 0, 0); \
        } \
    } \
    __builtin_amdgcn_s_setprio(0); } while (0)

#define SMPV(SH, SL, jj, LOC) do { \
    if ((LOC) && (jj) == qlo) { \
        _Pragma("unroll") \
        for (int nt = 0; nt < 4; ++nt) \
            _Pragma("unroll") \
            for (int r = 0; r < 4; ++r) { \
                int kg = (jj)*64 + nt*16 + quad*4 + r; \
                if (kg > rlo + lr) (SL)[nt][r] = -INFINITY; \
            } \
    } \
    _Pragma("unroll") \
    for (int nt = 0; nt < 4; ++nt) { \
        float e0 = __builtin_amdgcn_exp2f((SH)[nt][0]); \
        float e1 = __builtin_amdgcn_exp2f((SH)[nt][1]); \
        float e2 = __builtin_amdgcn_exp2f((SH)[nt][2]); \
        float e3 = __builtin_amdgcn_exp2f((SH)[nt][3]); \
        lsumH += (e0 + e1) + (e2 + e3); \
        ushort4 w; w.x = f2bf(e0); w.y = f2bf(e1); w.z = f2bf(e2); w.w = f2bf(e3); \
        *reinterpret_cast<ushort4*>(PsH + off64[nt]) = w; \
    } \
    if (LOC) { \
        _Pragma("unroll") \
        for (int nt = 0; nt < 4; ++nt) { \
            float e0 = __builtin_amdgcn_exp2f((SL)[nt][0]); \
            float e1 = __builtin_amdgcn_exp2f((SL)[nt][1]); \
            float e2 = __builtin_amdgcn_exp2f((SL)[nt][2]); \
            float e3 = __builtin_amdgcn_exp2f((SL)[nt][3]); \
            lsumL += (e0 + e1) + (e2 + e3); \
            ushort4 w; w.x = f2bf(e0); w.y = f2bf(e1); w.z = f2bf(e2); w.w = f2bf(e3); \
            *reinterpret_cast<ushort4*>(PsL + off64[nt]) = w; \
        } \
    } \
    __builtin_amdgcn_s_setprio(1); \
    _Pragma("unroll") \
    for (int kk = 0; kk < 2; ++kk) { \
        int rb = kk ? rb1 : rb0; \
        bf16x8 paH = *reinterpret_cast<const bf16x8*>(PsH + rb); \
        bf16x8 paL = paH; \
        if (LOC) paL = *reinterpret_cast<const bf16x8*>(PsL + rb); \
        _Pragma("unroll") \
        for (int nt = 0; nt < 4; ++nt) { \
            bf16x8 vb = *reinterpret_cast<const bf16x8*>(VsV + rb + nt*1024); \
            OaH[nt] = __builtin_amdgcn_mfma_f32_16x16x32_bf16(paH, vb, OaH[nt], 0, 0, 0); \
            if (LOC) OaL[nt] = __builtin_amdgcn_mfma_f32_16x16x32_bf16(paL, vb, OaL[nt], 0, 0, 0); \
        } \
    } \
    __builtin_amdgcn_s_setprio(0); } while (0)

#define MASKH(SH) do { \
    _Pragma("unroll") \
    for (int nt = 0; nt < 4; ++nt) \
        _Pragma("unroll") \
        for (int r = 0; r < 4; ++r) { \
            int kg = qhi*64 + nt*16 + quad*4 + r; \
            if (kg > rhi + lr) (SH)[nt][r] = -INFINITY; \
        } } while (0)

#define ITER(SCH, SCL, SNH, SNL, jj) do { \
    const bool loN_ = ((jj) + 1 <= qlo); \
    const bool loC_ = ((jj) <= qlo); \
    QKC(SNH, SNL, KsK, loN_); \
    SMPV(SCH, SCL, (jj), loC_); \
    if ((jj) + 2 <= qhi) { WRITEBUF(KsW, VsW); } \
    if ((jj) + 3 <= qhi) { LOADREGS(); } \
    asm volatile("s_waitcnt lgkmcnt(0)" ::: "memory"); \
    __builtin_amdgcn_s_barrier(); \
    { u16* t_ = KsV; KsV = KsK; KsK = KsW; KsW = t_; } \
    { u16* t_ = VsV; VsV = VsK; VsK = VsW; VsW = t_; } \
} while (0)

    // ---- prologue: tiles 0,1 -> LDS; tile 2 in regs; Sa(0) ----
    LOADREGS(); WRITEBUF(Ks[0], Vs[0]);
    LOADREGS(); WRITEBUF(Ks[1], Vs[1]);
    LOADREGS();                              // tile 2 (qhi >= 16 always)
    asm volatile("s_waitcnt lgkmcnt(0)" ::: "memory");
    __builtin_amdgcn_s_barrier();

    f32x4 SAH[4], SAL[4], SBH[4], SBL[4];
    QKC(SAH, SAL, Ks[0], true);              // Sa(0); lo active at j=0

    // ---- main loop: qhi iterations (j = 0 .. qhi-1), 2x-unrolled ----
    int j = 0;
    for (; j + 2 <= qhi; j += 2) {
        ITER(SAH, SAL, SBH, SBL, j);
        ITER(SBH, SBL, SAH, SAL, j + 1);
    }
    bool curA = true;
    if (j < qhi) { ITER(SAH, SAL, SBH, SBL, j); ++j; curA = false; }

    // ---- epilogue iteration j = qhi: hi set only, diagonal mask ----
    if (curA) { MASKH(SAH); SMPV(SAH, SAL, -1, false); }
    else      { MASKH(SBH); SMPV(SBH, SBL, -1, false); }

#undef LOADREGS
#undef WRITEBUF
#undef QKC
#undef SMPV
#undef MASKH
#undef ITER

    // epilogue: full row sums (reduce across quads), normalize, store.
    int b = bh >> 4, h = bh & 15;
    float sH = lsumH;
    sH += __shfl_xor(sH, 16, 64);
    sH += __shfl_xor(sH, 32, 64);
    float sL = lsumL;
    sL += __shfl_xor(sL, 16, 64);
    sL += __shfl_xor(sL, 32, 64);
    #pragma unroll
    for (int r = 0; r < 4; ++r) {
        float invH = 1.f / __shfl(sH, quad*4 + r, 64);
        float invL = 1.f / __shfl(sL, quad*4 + r, 64);
        int qgH = rhi + quad*4 + r;
        int qgL = rlo + quad*4 + r;
        #pragma unroll
        for (int nt = 0; nt < 4; ++nt) {
            int d = nt*16 + lr;
            Ob[((size_t)b*T_ + qgH)*D_ + h*HS_ + d] = f2bf(OaH[nt][r] * invH);
            Ob[((size_t)b*T_ + qgL)*D_ + h*HS_ + d] = f2bf(OaL[nt][r] * invL);
        }
    }
}

extern "C" void kernel_launch(void* const* d_in, const int* in_sizes, int n_in,
                              void* d_out, int out_size, void* d_ws, size_t ws_size,
                              hipStream_t stream) {
    (void)in_sizes; (void)n_in; (void)out_size; (void)ws_size;
    const float* x     = (const float*)d_in[0];
    const float* w_qkv = (const float*)d_in[1];
    const float* b_qkv = (const float*)d_in[2];
    const float* w_out = (const float*)d_in[3];
    const float* b_out = (const float*)d_in[4];
    float* out = (float*)d_out;

    char* ws = (char*)d_ws;
    u16* Xb    = (u16*)ws; ws += (size_t)M_ * D_ * 2;
    u16* WqkvT = (u16*)ws; ws += (size_t)3 * D_ * D_ * 2;
    u16* WoutT = (u16*)ws; ws += (size_t)D_ * D_ * 2;
    u16* Qb    = (u16*)ws; ws += (size_t)M_ * D_ * 2;
    u16* Kb    = (u16*)ws; ws += (size_t)M_ * D_ * 2;
    u16* Vt    = (u16*)ws; ws += (size_t)M_ * D_ * 2;
    u16* Ob    = (u16*)ws; ws += (size_t)M_ * D_ * 2;

    prep_kernel<<<8192, 256, 0, stream>>>(x, w_qkv, w_out, Xb, WqkvT, WoutT);
    gemm_qkv<<<dim3(16, 12), 512, 0, stream>>>(
        Xb, WqkvT, b_qkv, Qb, Kb, Vt);
    // paired q-tiles, swapped-QK, cross-iteration pipelined: 512 blocks
    attn_kernel<<<512, 256, 0, stream>>>(Qb, Kb, Vt, Ob);
    gemm_out<<<dim3(M_/128, D_/128), 256, 0, stream>>>(Ob, WoutT, b_out, out);
}

// Round 12
// 171.930 us; speedup vs baseline: 1.1897x; 1.1897x over previous
//
#include <hip/hip_runtime.h>
#include <math.h>

#define B_  2
#define T_  2048
#define D_  1024
#define H_  16
#define HS_ 64
#define M_  (B_*T_)   // 4096

typedef __bf16 bf16x8 __attribute__((ext_vector_type(8)));
typedef float  f32x4  __attribute__((ext_vector_type(4)));
typedef unsigned short u16;

// native HW cvt (v_cvt_pk_bf16_f32 when paired) — RNE, 1 inst vs 3-4 manual
static __device__ __forceinline__ u16 f2bf(float f) {
    __bf16 h = (__bf16)f;
    return *reinterpret_cast<u16*>(&h);
}

// async global->LDS, 16B/lane; LDS dest is lane-linear (base + lane*16).
static __device__ __forceinline__ void glds16(const u16* g, u16* l) {
    __builtin_amdgcn_global_load_lds(
        (const __attribute__((address_space(1))) void*)g,
        (__attribute__((address_space(3))) void*)l, 16, 0, 0);
}

// ---------------- fused prep: cast x, transpose+cast both weights ----------
__global__ __launch_bounds__(256) void prep_kernel(
    const float* __restrict__ x, const float* __restrict__ w_qkv,
    const float* __restrict__ w_out,
    u16* __restrict__ Xb, u16* __restrict__ WqkvT, u16* __restrict__ WoutT)
{
    int bid = blockIdx.x;
    if (bid < 4096) {                       // cast x
        int i = (bid * 256 + threadIdx.x) * 4;
        float4 v = *reinterpret_cast<const float4*>(x + i);
        ushort4 o;
        o.x = f2bf(v.x); o.y = f2bf(v.y); o.z = f2bf(v.z); o.w = f2bf(v.w);
        *reinterpret_cast<ushort4*>(Xb + i) = o;
        return;
    }
    const float* in; u16* out; int C; int c0, r0;
    if (bid < 4096 + 3072) {                // w_qkv (D x 3D) -> (3D x D)
        int t = bid - 4096;
        in = w_qkv; out = WqkvT; C = 3 * D_;
        c0 = (t % 96) * 32; r0 = (t / 96) * 32;
    } else {                                // w_out (D x D) -> (D x D)
        int t = bid - 7168;
        in = w_out; out = WoutT; C = D_;
        c0 = (t & 31) * 32; r0 = (t >> 5) * 32;
    }
    __shared__ float tile[32][33];
    int tr = threadIdx.x >> 3, tc4 = (threadIdx.x & 7) * 4;
    float4 v = *reinterpret_cast<const float4*>(in + (size_t)(r0 + tr) * C + c0 + tc4);
    tile[tr][tc4+0] = v.x; tile[tr][tc4+1] = v.y;
    tile[tr][tc4+2] = v.z; tile[tr][tc4+3] = v.w;
    __syncthreads();
    ushort4 o;
    o.x = f2bf(tile[tc4+0][tr]); o.y = f2bf(tile[tc4+1][tr]);
    o.z = f2bf(tile[tc4+2][tr]); o.w = f2bf(tile[tc4+3][tr]);
    *reinterpret_cast<ushort4*>(out + (size_t)(c0 + tr) * D_ + r0 + tc4) = o;
}

// ---------------- QKV GEMM: m201-style 4-phase-per-K-tile pipeline ---------
// 256x256 tile, BK=64, 8 waves (2M x 4N), 512 thr, 128 KiB LDS (2 dbuf).
// Per K-tile, 4 phases, each {ds_read subtile | stage one region of t+1 |
// bar | lgkm0 | 16 MFMA | bar}; vmcnt(4) only at phases B and D.
__global__ __launch_bounds__(512, 2) void gemm_qkv(
    const u16* __restrict__ A, const u16* __restrict__ Bt,
    const float* __restrict__ bias,
    u16* __restrict__ Qb, u16* __restrict__ Kb, u16* __restrict__ Vt)
{
    constexpr int K  = D_;        // 1024
    constexpr int NT = K / 64;    // 16

    __shared__ u16 LDS[2][2][2][8192];  // [buf][A|B][khalf][256r x 32k swz] = 128 KiB

    const int tid  = threadIdx.x;
    const int lane = tid & 63, wave = tid >> 6;
    const int wm = wave >> 2, wn = wave & 3;       // 2 x 4
    const int quad = lane >> 4, lr = lane & 15;
    const int bm = blockIdx.x, bn = blockIdx.y;

    const u16* Ab = A  + (size_t)(bm * 256) * K;
    const u16* Bb = Bt + (size_t)(bn * 256) * K;

    const int r0 = tid >> 2;
    const int c0 = (tid & 3) ^ ((tid >> 3) & 3);
    const u16* sA0 = Ab + (size_t)r0 * K + c0 * 8;
    const u16* sA1 = sA0 + (size_t)128 * K;
    const u16* sB0 = Bb + (size_t)r0 * K + c0 * 8;
    const u16* sB1 = sB0 + (size_t)128 * K;
    const int d0 = tid * 8, d1 = (tid + 512) * 8;

    const int swz = (lr >> 1) & 3;
    const int eA = ((wm*128 + lr) * 4 + (quad ^ swz)) * 8;
    const int eB = ((wn*64  + lr) * 4 + (quad ^ swz)) * 8;

    f32x4 acc[8][4] = {};

#define STG(mat, kh, tt) do { \
        u16* _d = &LDS[(tt) & 1][mat][kh][0]; \
        const int _ko = (tt) * 64 + (kh) * 32; \
        glds16(((mat) ? sB0 : sA0) + _ko, _d + d0); \
        glds16(((mat) ? sB1 : sA1) + _ko, _d + d1); \
    } while (0)

#define MFMA_QUAD(mh) do { \
        __builtin_amdgcn_s_setprio(1); \
        _Pragma("unroll") \
        for (int i_ = 0; i_ < 4; ++i_) \
            _Pragma("unroll") \
            for (int j_ = 0; j_ < 4; ++j_) \
                acc[(mh)*4 + i_][j_] = __builtin_amdgcn_mfma_f32_16x16x32_bf16( \
                    a[i_], b[j_], acc[(mh)*4 + i_][j_], 0, 0, 0); \
        __builtin_amdgcn_s_setprio(0); \
    } while (0)

    STG(0,0,0); STG(1,0,0); STG(0,1,0); STG(1,1,0);
    asm volatile("s_waitcnt vmcnt(4)" ::: "memory");
    __builtin_amdgcn_s_barrier();

    for (int t = 0; t < NT; ++t) {
        const int cb = t & 1;
        const bool last = (t == NT - 1);
        const u16* Ar0 = &LDS[cb][0][0][0];
        const u16* Ar1 = &LDS[cb][0][1][0];
        const u16* Br0 = &LDS[cb][1][0][0];
        const u16* Br1 = &LDS[cb][1][1][0];
        bf16x8 a[4], b[4];

        // ---- phase A: k0, m-frags 0-3 (+ b k0) ----
        #pragma unroll
        for (int i = 0; i < 4; ++i) a[i] = *reinterpret_cast<const bf16x8*>(Ar0 + eA + i*512);
        #pragma unroll
        for (int j = 0; j < 4; ++j) b[j] = *reinterpret_cast<const bf16x8*>(Br0 + eB + j*512);
        if (!last) STG(0,0,t+1);
        __builtin_amdgcn_s_barrier();
        asm volatile("s_waitcnt lgkmcnt(0)" ::: "memory");
        MFMA_QUAD(0);
        __builtin_amdgcn_s_barrier();

        // ---- phase B: k0, m-frags 4-7 (b reused) ----
        #pragma unroll
        for (int i = 0; i < 4; ++i) a[i] = *reinterpret_cast<const bf16x8*>(Ar0 + eA + (i+4)*512);
        if (!last) STG(1,0,t+1);
        __builtin_amdgcn_s_barrier();
        asm volatile("s_waitcnt lgkmcnt(0)" ::: "memory");
        MFMA_QUAD(1);
        if (!last) { asm volatile("s_waitcnt vmcnt(4)" ::: "memory"); }
        else       { asm volatile("s_waitcnt vmcnt(0)" ::: "memory"); }
        __builtin_amdgcn_s_barrier();

        // ---- phase C: k1, m-frags 0-3 (+ b k1) ----
        #pragma unroll
        for (int i = 0; i < 4; ++i) a[i] = *reinterpret_cast<const bf16x8*>(Ar1 + eA + i*512);
        #pragma unroll
        for (int j = 0; j < 4; ++j) b[j] = *reinterpret_cast<const bf16x8*>(Br1 + eB + j*512);
        if (!last) STG(0,1,t+1);
        __builtin_amdgcn_s_barrier();
        asm volatile("s_waitcnt lgkmcnt(0)" ::: "memory");
        MFMA_QUAD(0);
        __builtin_amdgcn_s_barrier();

        // ---- phase D: k1, m-frags 4-7 ----
        #pragma unroll
        for (int i = 0; i < 4; ++i) a[i] = *reinterpret_cast<const bf16x8*>(Ar1 + eA + (i+4)*512);
        if (!last) STG(1,1,t+1);
        __builtin_amdgcn_s_barrier();
        asm volatile("s_waitcnt lgkmcnt(0)" ::: "memory");
        MFMA_QUAD(1);
        asm volatile("s_waitcnt vmcnt(4)" ::: "memory");
        __builtin_amdgcn_s_barrier();
    }
#undef STG
#undef MFMA_QUAD

    // -------- epilogue: scatter to Q (scale folded) / K / V^T --------
    #pragma unroll
    for (int i = 0; i < 8; ++i) {
        int m0 = bm*256 + wm*128 + i*16 + quad*4;   // 4-aligned
        #pragma unroll
        for (int j = 0; j < 4; ++j) {
            int ncol = bn*256 + wn*64 + j*16 + lr;
            float bv = bias[ncol];
            float v4[4];
            #pragma unroll
            for (int r = 0; r < 4; ++r) v4[r] = acc[i][j][r] + bv;
            int bb = m0 >> 11, t0 = m0 & (T_ - 1);
            int s = ncol >> 10, rem = ncol & 1023;
            int h = rem >> 6, d = rem & 63;
            int bh = bb * H_ + h;
            if (s == 0) {
                // fold softmax scale AND log2(e) (attn uses exp2): 0.125*log2e
                #pragma unroll
                for (int r = 0; r < 4; ++r)
                    Qb[((size_t)bh*T_ + t0 + r)*HS_ + d] = f2bf(v4[r] * 0.1803368801111244f);
            } else if (s == 1) {
                #pragma unroll
                for (int r = 0; r < 4; ++r)
                    Kb[((size_t)bh*T_ + t0 + r)*HS_ + d] = f2bf(v4[r]);
            } else {
                ushort4 o;   // consecutive t -> one 8B store
                o.x = f2bf(v4[0]); o.y = f2bf(v4[1]);
                o.z = f2bf(v4[2]); o.w = f2bf(v4[3]);
                *reinterpret_cast<ushort4*>(&Vt[((size_t)bh*HS_ + d)*T_ + t0]) = o;
            }
        }
    }
}

// ---------------- out-proj GEMM: 2-phase-per-K-tile pipeline, 2 blk/CU -----
__global__ __launch_bounds__(256, 2) void gemm_out(
    const u16* __restrict__ A, const u16* __restrict__ Bt,
    const float* __restrict__ bias, float* __restrict__ Cf)
{
    constexpr int K  = D_;        // 1024
    constexpr int N  = D_;
    constexpr int NT = K / 64;    // 16

    __shared__ u16 LDS[2][2][2][4096];  // [buf][A|B][khalf][128r x 32k swz] = 64 KiB

    const int tid  = threadIdx.x;
    const int lane = tid & 63, wave = tid >> 6;
    const int wm = wave >> 1, wn = wave & 1;       // 2 x 2
    const int quad = lane >> 4, lr = lane & 15;
    const int bm = blockIdx.x, bn = blockIdx.y;

    const u16* Ab = A  + (size_t)(bm * 128) * K;
    const u16* Bb = Bt + (size_t)(bn * 128) * K;

    const int r0 = tid >> 2;
    const int c0 = (tid & 3) ^ ((tid >> 3) & 3);
    const u16* sA0 = Ab + (size_t)r0 * K + c0 * 8;
    const u16* sA1 = sA0 + (size_t)64 * K;
    const u16* sB0 = Bb + (size_t)r0 * K + c0 * 8;
    const u16* sB1 = sB0 + (size_t)64 * K;
    const int d0 = tid * 8, d1 = (tid + 256) * 8;

    const int swz = (lr >> 1) & 3;
    const int eA = ((wm*64 + lr) * 4 + (quad ^ swz)) * 8;
    const int eB = ((wn*64 + lr) * 4 + (quad ^ swz)) * 8;

    f32x4 acc[4][4] = {};

#define STGO(kh, tt) do { \
        const int _ko = (tt) * 64 + (kh) * 32; \
        glds16(sA0 + _ko, &LDS[(tt) & 1][0][kh][0] + d0); \
        glds16(sA1 + _ko, &LDS[(tt) & 1][0][kh][0] + d1); \
        glds16(sB0 + _ko, &LDS[(tt) & 1][1][kh][0] + d0); \
        glds16(sB1 + _ko, &LDS[(tt) & 1][1][kh][0] + d1); \
    } while (0)

    // prologue: stage tile 0 (both k-halves); k0 must land, k1 stays in flight
    STGO(0, 0); STGO(1, 0);
    asm volatile("s_waitcnt vmcnt(4)" ::: "memory");
    __builtin_amdgcn_s_barrier();

    for (int t = 0; t < NT; ++t) {
        const int cb = t & 1;
        const bool last = (t == NT - 1);
        bf16x8 a[4], b[4];

        // ---- phase 0: k-half 0 ----
        {
            const u16* Ar = &LDS[cb][0][0][0];
            const u16* Br = &LDS[cb][1][0][0];
            #pragma unroll
            for (int i = 0; i < 4; ++i) a[i] = *reinterpret_cast<const bf16x8*>(Ar + eA + i*512);
            #pragma unroll
            for (int j = 0; j < 4; ++j) b[j] = *reinterpret_cast<const bf16x8*>(Br + eB + j*512);
            if (!last) STGO(0, t+1);
            __builtin_amdgcn_s_barrier();
            asm volatile("s_waitcnt lgkmcnt(0)" ::: "memory");
            __builtin_amdgcn_s_setprio(1);
            #pragma unroll
            for (int i = 0; i < 4; ++i)
                #pragma unroll
                for (int j = 0; j < 4; ++j)
                    acc[i][j] = __builtin_amdgcn_mfma_f32_16x16x32_bf16(a[i], b[j], acc[i][j], 0, 0, 0);
            __builtin_amdgcn_s_setprio(0);
            if (!last) { asm volatile("s_waitcnt vmcnt(4)" ::: "memory"); }
            else       { asm volatile("s_waitcnt vmcnt(0)" ::: "memory"); }
            __builtin_amdgcn_s_barrier();
        }

        // ---- phase 1: k-half 1 ----
        {
            const u16* Ar = &LDS[cb][0][1][0];
            const u16* Br = &LDS[cb][1][1][0];
            #pragma unroll
            for (int i = 0; i < 4; ++i) a[i] = *reinterpret_cast<const bf16x8*>(Ar + eA + i*512);
            #pragma unroll
            for (int j = 0; j < 4; ++j) b[j] = *reinterpret_cast<const bf16x8*>(Br + eB + j*512);
            if (!last) STGO(1, t+1);
            __builtin_amdgcn_s_barrier();
            asm volatile("s_waitcnt lgkmcnt(0)" ::: "memory");
            __builtin_amdgcn_s_setprio(1);
            #pragma unroll
            for (int i = 0; i < 4; ++i)
                #pragma unroll
                for (int j = 0; j < 4; ++j)
                    acc[i][j] = __builtin_amdgcn_mfma_f32_16x16x32_bf16(a[i], b[j], acc[i][j], 0, 0, 0);
            __builtin_amdgcn_s_setprio(0);
            if (!last) { asm volatile("s_waitcnt vmcnt(4)" ::: "memory"); }
            __builtin_amdgcn_s_barrier();
        }
    }
#undef STGO

    // -------- epilogue: coalesced f32 rows --------
    #pragma unroll
    for (int i = 0; i < 4; ++i) {
        int m0 = bm*128 + wm*64 + i*16 + quad*4;
        #pragma unroll
        for (int j = 0; j < 4; ++j) {
            int ncol = bn*128 + wn*64 + j*16 + lr;
            float bv = bias[ncol];
            #pragma unroll
            for (int r = 0; r < 4; ++r)
                Cf[(size_t)(m0 + r) * N + ncol] = acc[i][j][r] + bv;
        }
    }
}

// ---------------- Flash attention (causal), bf16 MFMA ----------------
// 1024 blocks x 256 thr. Session-best attn variant (measured in the 171.4 us
// total): reg-staged prefetch, 32 KB LDS, per-wave P round-trip.
__global__ __launch_bounds__(256) void attn_kernel(
    const u16* __restrict__ Qb, const u16* __restrict__ Kb,
    const u16* __restrict__ Vt, u16* __restrict__ Ob)
{
    __shared__ u16 Ks[64 * 64];        // [key][d], swizzled chunks, 8 KB
    __shared__ u16 Vs[64 * 64];        // [d][key], swizzled chunks, 8 KB
    __shared__ u16 Ps[4][16 * 64];     // per-wave P (16 q x 64 key), swizzled

    int tid  = threadIdx.x;
    int lane = tid & 63, wave = tid >> 6;          // wave 0..3
    int quad = lane >> 4, lr = lane & 15;

    int lin = blockIdx.x;                          // 1024 blocks
    int bh  = (lin & 7) + 8 * ((lin >> 3) & 3);    // XCD-local bh
    int idx = lin >> 5;                            // 0..31
    int qt  = idx < 16 ? idx : 47 - idx;           // balanced pair mapping
    int qw  = qt * 64 + wave * 16;                 // wave's 16 query rows

    // Q fragments (A-layout); 1/sqrt(HS)*log2e pre-folded upstream
    const u16* Qp = Qb + ((size_t)bh * T_ + qw) * HS_;
    bf16x8 qf[2];
    #pragma unroll
    for (int h2 = 0; h2 < 2; ++h2)
        qf[h2] = *reinterpret_cast<const bf16x8*>(Qp + lr*HS_ + h2*32 + quad*8);

    f32x4 Oa[4] = {};
    float lrow[4] = {0.f, 0.f, 0.f, 0.f};

    // ---- loop-invariant LDS addresses (u16-element offsets) ----
    int e      = quad ^ (lr & 7);
    int rb0    = (lr * 8 + e) * 8;          // kk=0 base (chunk-slot*8 u16)
    int rb1    = (lr * 8 + (e ^ 4)) * 8;    // kk=1 base
    int offw[4][4];
    #pragma unroll
    for (int nt = 0; nt < 4; ++nt)
        #pragma unroll
        for (int r = 0; r < 4; ++r) {
            int prow = quad*4 + r;
            offw[nt][r] = (prow*8 + ((nt*2 + (lr >> 3)) ^ (prow & 7)))*8 + (lr & 7);
        }
    u16* Psw = Ps[wave];

    // staging: 256 thr x 2 chunks per matrix; swizzle via source redirect
    int srow = tid >> 3;
    int scol = ((tid & 7) ^ (srow & 7)) * 8;
    const u16* kp0 = Kb + ((size_t)bh*T_ + srow     )*HS_ + scol;
    const u16* kp1 = Kb + ((size_t)bh*T_ + srow + 32)*HS_ + scol;
    const u16* vp0 = Vt + ((size_t)bh*HS_ + srow     )*T_ + scol;
    const u16* vp1 = Vt + ((size_t)bh*HS_ + srow + 32)*T_ + scol;

    bf16x8 kpre0 = *reinterpret_cast<const bf16x8*>(kp0);
    bf16x8 kpre1 = *reinterpret_cast<const bf16x8*>(kp1);
    bf16x8 vpre0 = *reinterpret_cast<const bf16x8*>(vp0);
    bf16x8 vpre1 = *reinterpret_cast<const bf16x8*>(vp1);

    for (int jt = 0; jt <= qt; ++jt) {
        __syncthreads();
        reinterpret_cast<bf16x8*>(Ks)[tid]       = kpre0;
        reinterpret_cast<bf16x8*>(Ks)[tid + 256] = kpre1;
        reinterpret_cast<bf16x8*>(Vs)[tid]       = vpre0;
        reinterpret_cast<bf16x8*>(Vs)[tid + 256] = vpre1;
        if (jt < qt) {
            kp0 += 64*HS_; kp1 += 64*HS_; vp0 += 64; vp1 += 64;
            kpre0 = *reinterpret_cast<const bf16x8*>(kp0);
            kpre1 = *reinterpret_cast<const bf16x8*>(kp1);
            vpre0 = *reinterpret_cast<const bf16x8*>(vp0);
            vpre1 = *reinterpret_cast<const bf16x8*>(vp1);
        }
        __syncthreads();

        // S = Q @ K^T  (imm offsets nt*1024 off the two precomputed bases)
        f32x4 Sa[4] = {};
        #pragma unroll
        for (int nt = 0; nt < 4; ++nt) {
            bf16x8 bk0 = *reinterpret_cast<const bf16x8*>(Ks + rb0 + nt*1024);
            bf16x8 bk1 = *reinterpret_cast<const bf16x8*>(Ks + rb1 + nt*1024);
            Sa[nt] = __builtin_amdgcn_mfma_f32_16x16x32_bf16(qf[0], bk0, Sa[nt], 0, 0, 0);
            Sa[nt] = __builtin_amdgcn_mfma_f32_16x16x32_bf16(qf[1], bk1, Sa[nt], 0, 0, 0);
        }

        if (jt == qt) {   // causal mask in diagonal tile
            int kb = jt * 64;
            #pragma unroll
            for (int nt = 0; nt < 4; ++nt)
                #pragma unroll
                for (int r = 0; r < 4; ++r) {
                    int kg = kb + nt*16 + lr;
                    int qg = qw + quad*4 + r;
                    if (kg > qg) Sa[nt][r] = -INFINITY;
                }
        }

        // P = exp2(S)  (log2e pre-folded); per-lane row sums; P -> LDS
        #pragma unroll
        for (int nt = 0; nt < 4; ++nt)
            #pragma unroll
            for (int r = 0; r < 4; ++r) {
                float pv = __builtin_amdgcn_exp2f(Sa[nt][r]);
                lrow[r] += pv;
                Psw[offw[nt][r]] = f2bf(pv);
            }

        // O += P @ V  (same-wave LDS ordering via lgkmcnt; no barrier)
        #pragma unroll
        for (int kk = 0; kk < 2; ++kk) {
            int rb = kk ? rb1 : rb0;
            bf16x8 pa = *reinterpret_cast<const bf16x8*>(Psw + rb);
            #pragma unroll
            for (int nt = 0; nt < 4; ++nt) {
                bf16x8 vb = *reinterpret_cast<const bf16x8*>(Vs + rb + nt*1024);
                Oa[nt] = __builtin_amdgcn_mfma_f32_16x16x32_bf16(pa, vb, Oa[nt], 0, 0, 0);
            }
        }
    }

    // epilogue: reduce row sums across 16 col-lanes, normalize, store
    int b = bh >> 4, h = bh & 15;
    #pragma unroll
    for (int r = 0; r < 4; ++r) {
        float s = lrow[r];
        #pragma unroll
        for (int off = 8; off >= 1; off >>= 1)
            s += __shfl_xor(s, off, 64);
        float inv = 1.f / s;
        int qg = qw + quad*4 + r;
        #pragma unroll
        for (int nt = 0; nt < 4; ++nt) {
            int d = nt*16 + lr;
            Ob[((size_t)b*T_ + qg)*D_ + h*HS_ + d] = f2bf(Oa[nt][r] * inv);
        }
    }
}

extern "C" void kernel_launch(void* const* d_in, const int* in_sizes, int n_in,
                              void* d_out, int out_size, void* d_ws, size_t ws_size,
                              hipStream_t stream) {
    (void)in_sizes; (void)n_in; (void)out_size; (void)ws_size;
    const float* x     = (const float*)d_in[0];
    const float* w_qkv = (const float*)d_in[1];
    const float* b_qkv = (const float*)d_in[2];
    const float* w_out = (const float*)d_in[3];
    const float* b_out = (const float*)d_in[4];
    float* out = (float*)d_out;

    char* ws = (char*)d_ws;
    u16* Xb    = (u16*)ws; ws += (size_t)M_ * D_ * 2;
    u16* WqkvT = (u16*)ws; ws += (size_t)3 * D_ * D_ * 2;
    u16* WoutT = (u16*)ws; ws += (size_t)D_ * D_ * 2;
    u16* Qb    = (u16*)ws; ws += (size_t)M_ * D_ * 2;
    u16* Kb    = (u16*)ws; ws += (size_t)M_ * D_ * 2;
    u16* Vt    = (u16*)ws; ws += (size_t)M_ * D_ * 2;
    u16* Ob    = (u16*)ws; ws += (size_t)M_ * D_ * 2;

    prep_kernel<<<8192, 256, 0, stream>>>(x, w_qkv, w_out, Xb, WqkvT, WoutT);
    // QKV: 256x256 tile, 8 waves, 4-phase pipelined K-loop (T3+T4)
    gemm_qkv<<<dim3(M_/256, 3*D_/256), 512, 0, stream>>>(
        Xb, WqkvT, b_qkv, Qb, Kb, Vt);
    attn_kernel<<<1024, 256, 0, stream>>>(Qb, Kb, Vt, Ob);
    // out-proj: 128x128, 2-phase pipelined, 256 blocks at 2 blocks/CU
    gemm_out<<<dim3(M_/128, D_/128), 256, 0, stream>>>(Ob, WoutT, b_out, out);
}

// Round 13
// 171.714 us; speedup vs baseline: 1.1912x; 1.0013x over previous
//
#include <hip/hip_runtime.h>
#include <math.h>

#define B_  2
#define T_  2048
#define D_  1024
#define H_  16
#define HS_ 64
#define M_  (B_*T_)   // 4096

typedef __bf16 bf16x8 __attribute__((ext_vector_type(8)));
typedef float  f32x4  __attribute__((ext_vector_type(4)));
typedef unsigned short u16;

// native HW cvt (v_cvt_pk_bf16_f32 when paired) — RNE, 1 inst vs 3-4 manual
static __device__ __forceinline__ u16 f2bf(float f) {
    __bf16 h = (__bf16)f;
    return *reinterpret_cast<u16*>(&h);
}

// async global->LDS, 16B/lane; LDS dest is lane-linear (base + lane*16).
static __device__ __forceinline__ void glds16(const u16* g, u16* l) {
    __builtin_amdgcn_global_load_lds(
        (const __attribute__((address_space(1))) void*)g,
        (__attribute__((address_space(3))) void*)l, 16, 0, 0);
}

// ---------------- fused prep: cast x, transpose+cast both weights ----------
__global__ __launch_bounds__(256) void prep_kernel(
    const float* __restrict__ x, const float* __restrict__ w_qkv,
    const float* __restrict__ w_out,
    u16* __restrict__ Xb, u16* __restrict__ WqkvT, u16* __restrict__ WoutT)
{
    int bid = blockIdx.x;
    if (bid < 4096) {                       // cast x
        int i = (bid * 256 + threadIdx.x) * 4;
        float4 v = *reinterpret_cast<const float4*>(x + i);
        ushort4 o;
        o.x = f2bf(v.x); o.y = f2bf(v.y); o.z = f2bf(v.z); o.w = f2bf(v.w);
        *reinterpret_cast<ushort4*>(Xb + i) = o;
        return;
    }
    const float* in; u16* out; int C; int c0, r0;
    if (bid < 4096 + 3072) {                // w_qkv (D x 3D) -> (3D x D)
        int t = bid - 4096;
        in = w_qkv; out = WqkvT; C = 3 * D_;
        c0 = (t % 96) * 32; r0 = (t / 96) * 32;
    } else {                                // w_out (D x D) -> (D x D)
        int t = bid - 7168;
        in = w_out; out = WoutT; C = D_;
        c0 = (t & 31) * 32; r0 = (t >> 5) * 32;
    }
    __shared__ float tile[32][33];
    int tr = threadIdx.x >> 3, tc4 = (threadIdx.x & 7) * 4;
    float4 v = *reinterpret_cast<const float4*>(in + (size_t)(r0 + tr) * C + c0 + tc4);
    tile[tr][tc4+0] = v.x; tile[tr][tc4+1] = v.y;
    tile[tr][tc4+2] = v.z; tile[tr][tc4+3] = v.w;
    __syncthreads();
    ushort4 o;
    o.x = f2bf(tile[tc4+0][tr]); o.y = f2bf(tile[tc4+1][tr]);
    o.z = f2bf(tile[tc4+2][tr]); o.w = f2bf(tile[tc4+3][tr]);
    *reinterpret_cast<ushort4*>(out + (size_t)(c0 + tr) * D_ + r0 + tc4) = o;
}

// ---------------- QKV GEMM: 4-phase pipeline, 256x192 tile, FULL machine ---
// Grid 16x16 = 256 blocks = exactly 1/CU (was 192 blocks -> 25% of CUs idle).
// 8 waves (2M x 4N), per-wave 128x48 (acc[8][3]). LDS 112 KiB: A 2x32K,
// B 2x24K. B-tile (192x64 = 1536 chunks) staged as 3 uniform regions of
// 512 chunks (1 load/thread each) so the per-wave vmcnt ledger stays exact:
//   issue t+1: {A-k0 x2, B-R0, B-R1} at phase A; {A-k1 x2, B-R2} at phase C.
//   vmcnt(4) end of phase B (lands t's last-3 before phase C's k1 reads);
//   vmcnt(3) end of phase D (lands t+1's first-4 before next phase A).
// In-flight 3..7, never drained in the loop.
__global__ __launch_bounds__(512, 2) void gemm_qkv(
    const u16* __restrict__ A, const u16* __restrict__ Bt,
    const float* __restrict__ bias,
    u16* __restrict__ Qb, u16* __restrict__ Kb, u16* __restrict__ Vt)
{
    constexpr int K  = D_;        // 1024
    constexpr int NT = K / 64;    // 16

    __shared__ u16 LDSA[2][2][8192];   // [buf][khalf][256r x 32k swz] = 64 KB
    __shared__ u16 LDSB[2][2][6144];   // [buf][khalf][192r x 32k swz] = 48 KB

    const int tid  = threadIdx.x;
    const int lane = tid & 63, wave = tid >> 6;
    const int wm = wave >> 2, wn = wave & 3;       // 2 x 4
    const int quad = lane >> 4, lr = lane & 15;
    const int bm = blockIdx.x, bn = blockIdx.y;    // 16 x 16

    const u16* Ab = A  + (size_t)(bm * 256) * K;
    const u16* Bb = Bt + (size_t)(bn * 192) * K;

    // A staging: per khalf region = 1024 chunks; thread covers {tid, tid+512}
    const int r0 = tid >> 2;
    const int c0 = (tid & 3) ^ ((tid >> 3) & 3);
    const u16* sA0 = Ab + (size_t)r0 * K + c0 * 8;
    const u16* sA1 = sA0 + (size_t)128 * K;
    const int dA0 = tid * 8, dA1 = (tid + 512) * 8;

    // B staging: 3 regions of 512 chunks spanning both khalves contiguously.
    const u16* sB[3]; int dB[3];
    #pragma unroll
    for (int rg = 0; rg < 3; ++rg) {
        int ti = 512 * rg + tid;                   // 0..1535
        int kh = ti >= 768;
        int cb = ti - kh * 768;
        int row = cb >> 2;
        int c  = (cb & 3) ^ ((row >> 1) & 3);
        sB[rg] = Bb + (size_t)row * K + kh * 32 + c * 8;
        dB[rg] = ti * 8;                           // u16 off from LDSB[buf][0]
    }

    // loop-invariant read bases; frag i adds i*512
    const int swz = (lr >> 1) & 3;
    const int eA = ((wm*128 + lr) * 4 + (quad ^ swz)) * 8;
    const int eB = ((wn*48  + lr) * 4 + (quad ^ swz)) * 8;

    f32x4 acc[8][3] = {};

#define STG_F4(tt) do { /* t+1 first-4: A-k0 x2, B-R0, B-R1 */ \
        u16* _da = &LDSA[(tt) & 1][0][0]; \
        u16* _db = &LDSB[(tt) & 1][0][0]; \
        const int _ko = (tt) * 64; \
        glds16(sA0 + _ko, _da + dA0); \
        glds16(sA1 + _ko, _da + dA1); \
        glds16(sB[0] + _ko, _db + dB[0]); \
        glds16(sB[1] + _ko, _db + dB[1]); \
    } while (0)

#define STG_L3(tt) do { /* t+1 last-3: A-k1 x2, B-R2 */ \
        u16* _da = &LDSA[(tt) & 1][1][0]; \
        u16* _db = &LDSB[(tt) & 1][0][0]; \
        const int _ko = (tt) * 64; \
        glds16(sA0 + _ko + 32, _da + dA0); \
        glds16(sA1 + _ko + 32, _da + dA1); \
        glds16(sB[2] + _ko, _db + dB[2]); \
    } while (0)

#define MFMA_QUAD(mh) do { \
        __builtin_amdgcn_s_setprio(1); \
        _Pragma("unroll") \
        for (int i_ = 0; i_ < 4; ++i_) \
            _Pragma("unroll") \
            for (int j_ = 0; j_ < 3; ++j_) \
                acc[(mh)*4 + i_][j_] = __builtin_amdgcn_mfma_f32_16x16x32_bf16( \
                    a[i_], b[j_], acc[(mh)*4 + i_][j_], 0, 0, 0); \
        __builtin_amdgcn_s_setprio(0); \
    } while (0)

    // prologue: tile 0's 7 loads; land first-4, keep last-3 in flight
    STG_F4(0); STG_L3(0);
    asm volatile("s_waitcnt vmcnt(3)" ::: "memory");
    __builtin_amdgcn_s_barrier();

    for (int t = 0; t < NT; ++t) {
        const int cb = t & 1;
        const bool last = (t == NT - 1);
        const u16* Ar0 = &LDSA[cb][0][0];
        const u16* Ar1 = &LDSA[cb][1][0];
        const u16* Br0 = &LDSB[cb][0][0];
        const u16* Br1 = &LDSB[cb][1][0];
        bf16x8 a[4], b[3];

        // ---- phase A: k0, m-frags 0-3 (+ b k0) | issue t+1 first-4 ----
        #pragma unroll
        for (int i = 0; i < 4; ++i) a[i] = *reinterpret_cast<const bf16x8*>(Ar0 + eA + i*512);
        #pragma unroll
        for (int j = 0; j < 3; ++j) b[j] = *reinterpret_cast<const bf16x8*>(Br0 + eB + j*512);
        if (!last) STG_F4(t+1);
        __builtin_amdgcn_s_barrier();
        asm volatile("s_waitcnt lgkmcnt(0)" ::: "memory");
        MFMA_QUAD(0);
        __builtin_amdgcn_s_barrier();

        // ---- phase B: k0, m-frags 4-7 (b reused) | land t's last-3 ----
        #pragma unroll
        for (int i = 0; i < 4; ++i) a[i] = *reinterpret_cast<const bf16x8*>(Ar0 + eA + (i+4)*512);
        __builtin_amdgcn_s_barrier();
        asm volatile("s_waitcnt lgkmcnt(0)" ::: "memory");
        MFMA_QUAD(1);
        if (!last) { asm volatile("s_waitcnt vmcnt(4)" ::: "memory"); }
        else       { asm volatile("s_waitcnt vmcnt(0)" ::: "memory"); }
        __builtin_amdgcn_s_barrier();

        // ---- phase C: k1, m-frags 0-3 (+ b k1) | issue t+1 last-3 ----
        #pragma unroll
        for (int i = 0; i < 4; ++i) a[i] = *reinterpret_cast<const bf16x8*>(Ar1 + eA + i*512);
        #pragma unroll
        for (int j = 0; j < 3; ++j) b[j] = *reinterpret_cast<const bf16x8*>(Br1 + eB + j*512);
        if (!last) STG_L3(t+1);
        __builtin_amdgcn_s_barrier();
        asm volatile("s_waitcnt lgkmcnt(0)" ::: "memory");
        MFMA_QUAD(0);
        __builtin_amdgcn_s_barrier();

        // ---- phase D: k1, m-frags 4-7 | land t+1's first-4 ----
        #pragma unroll
        for (int i = 0; i < 4; ++i) a[i] = *reinterpret_cast<const bf16x8*>(Ar1 + eA + (i+4)*512);
        __builtin_amdgcn_s_barrier();
        asm volatile("s_waitcnt lgkmcnt(0)" ::: "memory");
        MFMA_QUAD(1);
        asm volatile("s_waitcnt vmcnt(3)" ::: "memory");
        __builtin_amdgcn_s_barrier();
    }
#undef STG_F4
#undef STG_L3
#undef MFMA_QUAD

    // -------- epilogue: scatter to Q (scale folded) / K / V^T --------
    #pragma unroll
    for (int i = 0; i < 8; ++i) {
        int m0 = bm*256 + wm*128 + i*16 + quad*4;   // 4-aligned
        #pragma unroll
        for (int j = 0; j < 3; ++j) {
            int ncol = bn*192 + wn*48 + j*16 + lr;
            float bv = bias[ncol];
            float v4[4];
            #pragma unroll
            for (int r = 0; r < 4; ++r) v4[r] = acc[i][j][r] + bv;
            int bb = m0 >> 11, t0 = m0 & (T_ - 1);
            int s = ncol >> 10, rem = ncol & 1023;
            int h = rem >> 6, d = rem & 63;
            int bh = bb * H_ + h;
            if (s == 0) {
                // fold softmax scale AND log2(e) (attn uses exp2): 0.125*log2e
                #pragma unroll
                for (int r = 0; r < 4; ++r)
                    Qb[((size_t)bh*T_ + t0 + r)*HS_ + d] = f2bf(v4[r] * 0.1803368801111244f);
            } else if (s == 1) {
                #pragma unroll
                for (int r = 0; r < 4; ++r)
                    Kb[((size_t)bh*T_ + t0 + r)*HS_ + d] = f2bf(v4[r]);
            } else {
                ushort4 o;   // consecutive t -> one 8B store
                o.x = f2bf(v4[0]); o.y = f2bf(v4[1]);
                o.z = f2bf(v4[2]); o.w = f2bf(v4[3]);
                *reinterpret_cast<ushort4*>(&Vt[((size_t)bh*HS_ + d)*T_ + t0]) = o;
            }
        }
    }
}

// ---------------- out-proj GEMM: 2-phase-per-K-tile pipeline, 2 blk/CU -----
__global__ __launch_bounds__(256, 2) void gemm_out(
    const u16* __restrict__ A, const u16* __restrict__ Bt,
    const float* __restrict__ bias, float* __restrict__ Cf)
{
    constexpr int K  = D_;        // 1024
    constexpr int N  = D_;
    constexpr int NT = K / 64;    // 16

    __shared__ u16 LDS[2][2][2][4096];  // [buf][A|B][khalf][128r x 32k swz] = 64 KiB

    const int tid  = threadIdx.x;
    const int lane = tid & 63, wave = tid >> 6;
    const int wm = wave >> 1, wn = wave & 1;       // 2 x 2
    const int quad = lane >> 4, lr = lane & 15;
    const int bm = blockIdx.x, bn = blockIdx.y;

    const u16* Ab = A  + (size_t)(bm * 128) * K;
    const u16* Bb = Bt + (size_t)(bn * 128) * K;

    const int r0 = tid >> 2;
    const int c0 = (tid & 3) ^ ((tid >> 3) & 3);
    const u16* sA0 = Ab + (size_t)r0 * K + c0 * 8;
    const u16* sA1 = sA0 + (size_t)64 * K;
    const u16* sB0 = Bb + (size_t)r0 * K + c0 * 8;
    const u16* sB1 = sB0 + (size_t)64 * K;
    const int d0 = tid * 8, d1 = (tid + 256) * 8;

    const int swz = (lr >> 1) & 3;
    const int eA = ((wm*64 + lr) * 4 + (quad ^ swz)) * 8;
    const int eB = ((wn*64 + lr) * 4 + (quad ^ swz)) * 8;

    f32x4 acc[4][4] = {};

#define STGO(kh, tt) do { \
        const int _ko = (tt) * 64 + (kh) * 32; \
        glds16(sA0 + _ko, &LDS[(tt) & 1][0][kh][0] + d0); \
        glds16(sA1 + _ko, &LDS[(tt) & 1][0][kh][0] + d1); \
        glds16(sB0 + _ko, &LDS[(tt) & 1][1][kh][0] + d0); \
        glds16(sB1 + _ko, &LDS[(tt) & 1][1][kh][0] + d1); \
    } while (0)

    // prologue: stage tile 0 (both k-halves); k0 must land, k1 stays in flight
    STGO(0, 0); STGO(1, 0);
    asm volatile("s_waitcnt vmcnt(4)" ::: "memory");
    __builtin_amdgcn_s_barrier();

    for (int t = 0; t < NT; ++t) {
        const int cb = t & 1;
        const bool last = (t == NT - 1);
        bf16x8 a[4], b[4];

        // ---- phase 0: k-half 0 ----
        {
            const u16* Ar = &LDS[cb][0][0][0];
            const u16* Br = &LDS[cb][1][0][0];
            #pragma unroll
            for (int i = 0; i < 4; ++i) a[i] = *reinterpret_cast<const bf16x8*>(Ar + eA + i*512);
            #pragma unroll
            for (int j = 0; j < 4; ++j) b[j] = *reinterpret_cast<const bf16x8*>(Br + eB + j*512);
            if (!last) STGO(0, t+1);
            __builtin_amdgcn_s_barrier();
            asm volatile("s_waitcnt lgkmcnt(0)" ::: "memory");
            __builtin_amdgcn_s_setprio(1);
            #pragma unroll
            for (int i = 0; i < 4; ++i)
                #pragma unroll
                for (int j = 0; j < 4; ++j)
                    acc[i][j] = __builtin_amdgcn_mfma_f32_16x16x32_bf16(a[i], b[j], acc[i][j], 0, 0, 0);
            __builtin_amdgcn_s_setprio(0);
            if (!last) { asm volatile("s_waitcnt vmcnt(4)" ::: "memory"); }
            else       { asm volatile("s_waitcnt vmcnt(0)" ::: "memory"); }
            __builtin_amdgcn_s_barrier();
        }

        // ---- phase 1: k-half 1 ----
        {
            const u16* Ar = &LDS[cb][0][1][0];
            const u16* Br = &LDS[cb][1][1][0];
            #pragma unroll
            for (int i = 0; i < 4; ++i) a[i] = *reinterpret_cast<const bf16x8*>(Ar + eA + i*512);
            #pragma unroll
            for (int j = 0; j < 4; ++j) b[j] = *reinterpret_cast<const bf16x8*>(Br + eB + j*512);
            if (!last) STGO(1, t+1);
            __builtin_amdgcn_s_barrier();
            asm volatile("s_waitcnt lgkmcnt(0)" ::: "memory");
            __builtin_amdgcn_s_setprio(1);
            #pragma unroll
            for (int i = 0; i < 4; ++i)
                #pragma unroll
                for (int j = 0; j < 4; ++j)
                    acc[i][j] = __builtin_amdgcn_mfma_f32_16x16x32_bf16(a[i], b[j], acc[i][j], 0, 0, 0);
            __builtin_amdgcn_s_setprio(0);
            if (!last) { asm volatile("s_waitcnt vmcnt(4)" ::: "memory"); }
            __builtin_amdgcn_s_barrier();
        }
    }
#undef STGO

    // -------- epilogue: coalesced f32 rows --------
    #pragma unroll
    for (int i = 0; i < 4; ++i) {
        int m0 = bm*128 + wm*64 + i*16 + quad*4;
        #pragma unroll
        for (int j = 0; j < 4; ++j) {
            int ncol = bn*128 + wn*64 + j*16 + lr;
            float bv = bias[ncol];
            #pragma unroll
            for (int r = 0; r < 4; ++r)
                Cf[(size_t)(m0 + r) * N + ncol] = acc[i][j][r] + bv;
        }
    }
}

// ---------------- Flash attention (causal), bf16 MFMA ----------------
// 1024 blocks x 256 thr. Session-best attn variant (R12-verified).
__global__ __launch_bounds__(256) void attn_kernel(
    const u16* __restrict__ Qb, const u16* __restrict__ Kb,
    const u16* __restrict__ Vt, u16* __restrict__ Ob)
{
    __shared__ u16 Ks[64 * 64];        // [key][d], swizzled chunks, 8 KB
    __shared__ u16 Vs[64 * 64];        // [d][key], swizzled chunks, 8 KB
    __shared__ u16 Ps[4][16 * 64];     // per-wave P (16 q x 64 key), swizzled

    int tid  = threadIdx.x;
    int lane = tid & 63, wave = tid >> 6;          // wave 0..3
    int quad = lane >> 4, lr = lane & 15;

    int lin = blockIdx.x;                          // 1024 blocks
    int bh  = (lin & 7) + 8 * ((lin >> 3) & 3);    // XCD-local bh
    int idx = lin >> 5;                            // 0..31
    int qt  = idx < 16 ? idx : 47 - idx;           // balanced pair mapping
    int qw  = qt * 64 + wave * 16;                 // wave's 16 query rows

    // Q fragments (A-layout); 1/sqrt(HS)*log2e pre-folded upstream
    const u16* Qp = Qb + ((size_t)bh * T_ + qw) * HS_;
    bf16x8 qf[2];
    #pragma unroll
    for (int h2 = 0; h2 < 2; ++h2)
        qf[h2] = *reinterpret_cast<const bf16x8*>(Qp + lr*HS_ + h2*32 + quad*8);

    f32x4 Oa[4] = {};
    float lrow[4] = {0.f, 0.f, 0.f, 0.f};

    // ---- loop-invariant LDS addresses (u16-element offsets) ----
    int e      = quad ^ (lr & 7);
    int rb0    = (lr * 8 + e) * 8;          // kk=0 base (chunk-slot*8 u16)
    int rb1    = (lr * 8 + (e ^ 4)) * 8;    // kk=1 base
    int offw[4][4];
    #pragma unroll
    for (int nt = 0; nt < 4; ++nt)
        #pragma unroll
        for (int r = 0; r < 4; ++r) {
            int prow = quad*4 + r;
            offw[nt][r] = (prow*8 + ((nt*2 + (lr >> 3)) ^ (prow & 7)))*8 + (lr & 7);
        }
    u16* Psw = Ps[wave];

    // staging: 256 thr x 2 chunks per matrix; swizzle via source redirect
    int srow = tid >> 3;
    int scol = ((tid & 7) ^ (srow & 7)) * 8;
    const u16* kp0 = Kb + ((size_t)bh*T_ + srow     )*HS_ + scol;
    const u16* kp1 = Kb + ((size_t)bh*T_ + srow + 32)*HS_ + scol;
    const u16* vp0 = Vt + ((size_t)bh*HS_ + srow     )*T_ + scol;
    const u16* vp1 = Vt + ((size_t)bh*HS_ + srow + 32)*T_ + scol;

    bf16x8 kpre0 = *reinterpret_cast<const bf16x8*>(kp0);
    bf16x8 kpre1 = *reinterpret_cast<const bf16x8*>(kp1);
    bf16x8 vpre0 = *reinterpret_cast<const bf16x8*>(vp0);
    bf16x8 vpre1 = *reinterpret_cast<const bf16x8*>(vp1);

    for (int jt = 0; jt <= qt; ++jt) {
        __syncthreads();
        reinterpret_cast<bf16x8*>(Ks)[tid]       = kpre0;
        reinterpret_cast<bf16x8*>(Ks)[tid + 256] = kpre1;
        reinterpret_cast<bf16x8*>(Vs)[tid]       = vpre0;
        reinterpret_cast<bf16x8*>(Vs)[tid + 256] = vpre1;
        if (jt < qt) {
            kp0 += 64*HS_; kp1 += 64*HS_; vp0 += 64; vp1 += 64;
            kpre0 = *reinterpret_cast<const bf16x8*>(kp0);
            kpre1 = *reinterpret_cast<const bf16x8*>(kp1);
            vpre0 = *reinterpret_cast<const bf16x8*>(vp0);
            vpre1 = *reinterpret_cast<const bf16x8*>(vp1);
        }
        __syncthreads();

        // S = Q @ K^T  (imm offsets nt*1024 off the two precomputed bases)
        f32x4 Sa[4] = {};
        #pragma unroll
        for (int nt = 0; nt < 4; ++nt) {
            bf16x8 bk0 = *reinterpret_cast<const bf16x8*>(Ks + rb0 + nt*1024);
            bf16x8 bk1 = *reinterpret_cast<const bf16x8*>(Ks + rb1 + nt*1024);
            Sa[nt] = __builtin_amdgcn_mfma_f32_16x16x32_bf16(qf[0], bk0, Sa[nt], 0, 0, 0);
            Sa[nt] = __builtin_amdgcn_mfma_f32_16x16x32_bf16(qf[1], bk1, Sa[nt], 0, 0, 0);
        }

        if (jt == qt) {   // causal mask in diagonal tile
            int kb = jt * 64;
            #pragma unroll
            for (int nt = 0; nt < 4; ++nt)
                #pragma unroll
                for (int r = 0; r < 4; ++r) {
                    int kg = kb + nt*16 + lr;
                    int qg = qw + quad*4 + r;
                    if (kg > qg) Sa[nt][r] = -INFINITY;
                }
        }

        // P = exp2(S)  (log2e pre-folded); per-lane row sums; P -> LDS
        #pragma unroll
        for (int nt = 0; nt < 4; ++nt)
            #pragma unroll
            for (int r = 0; r < 4; ++r) {
                float pv = __builtin_amdgcn_exp2f(Sa[nt][r]);
                lrow[r] += pv;
                Psw[offw[nt][r]] = f2bf(pv);
            }

        // O += P @ V  (same-wave LDS ordering via lgkmcnt; no barrier)
        #pragma unroll
        for (int kk = 0; kk < 2; ++kk) {
            int rb = kk ? rb1 : rb0;
            bf16x8 pa = *reinterpret_cast<const bf16x8*>(Psw + rb);
            #pragma unroll
            for (int nt = 0; nt < 4; ++nt) {
                bf16x8 vb = *reinterpret_cast<const bf16x8*>(Vs + rb + nt*1024);
                Oa[nt] = __builtin_amdgcn_mfma_f32_16x16x32_bf16(pa, vb, Oa[nt], 0, 0, 0);
            }
        }
    }

    // epilogue: reduce row sums across 16 col-lanes, normalize, store
    int b = bh >> 4, h = bh & 15;
    #pragma unroll
    for (int r = 0; r < 4; ++r) {
        float s = lrow[r];
        #pragma unroll
        for (int off = 8; off >= 1; off >>= 1)
            s += __shfl_xor(s, off, 64);
        float inv = 1.f / s;
        int qg = qw + quad*4 + r;
        #pragma unroll
        for (int nt = 0; nt < 4; ++nt) {
            int d = nt*16 + lr;
            Ob[((size_t)b*T_ + qg)*D_ + h*HS_ + d] = f2bf(Oa[nt][r] * inv);
        }
    }
}

extern "C" void kernel_launch(void* const* d_in, const int* in_sizes, int n_in,
                              void* d_out, int out_size, void* d_ws, size_t ws_size,
                              hipStream_t stream) {
    (void)in_sizes; (void)n_in; (void)out_size; (void)ws_size;
    const float* x     = (const float*)d_in[0];
    const float* w_qkv = (const float*)d_in[1];
    const float* b_qkv = (const float*)d_in[2];
    const float* w_out = (const float*)d_in[3];
    const float* b_out = (const float*)d_in[4];
    float* out = (float*)d_out;

    char* ws = (char*)d_ws;
    u16* Xb    = (u16*)ws; ws += (size_t)M_ * D_ * 2;
    u16* WqkvT = (u16*)ws; ws += (size_t)3 * D_ * D_ * 2;
    u16* WoutT = (u16*)ws; ws += (size_t)D_ * D_ * 2;
    u16* Qb    = (u16*)ws; ws += (size_t)M_ * D_ * 2;
    u16* Kb    = (u16*)ws; ws += (size_t)M_ * D_ * 2;
    u16* Vt    = (u16*)ws; ws += (size_t)M_ * D_ * 2;
    u16* Ob    = (u16*)ws; ws += (size_t)M_ * D_ * 2;

    prep_kernel<<<8192, 256, 0, stream>>>(x, w_qkv, w_out, Xb, WqkvT, WoutT);
    // QKV: 256x192 tile, 16x16 = 256 blocks = exactly 1 block/CU
    gemm_qkv<<<dim3(16, 16), 512, 0, stream>>>(
        Xb, WqkvT, b_qkv, Qb, Kb, Vt);
    attn_kernel<<<1024, 256, 0, stream>>>(Qb, Kb, Vt, Ob);
    // out-proj: 128x128, 2-phase pipelined, 256 blocks at 2 blocks/CU
    gemm_out<<<dim3(M_/128, D_/128), 256, 0, stream>>>(Ob, WoutT, b_out, out);
}